// Round 1
// 173.929 us; speedup vs baseline: 1.0096x; 1.0096x over previous
//
#include <hip/hip_runtime.h>
#include <math.h>

// Problem constants (from reference)
#define BB 4
#define HH 704
#define WW 704
#define MM 32
#define PP 128
#define NNEG 129
#define RR 1
#define GAIN 2.0f
#define HW (HH * WW)

// Only losses[-1] (batch b = B-1 = 3) is returned.
// Work items flattened, one per global thread g = blockIdx.x*64 + threadIdx.x:
//   [0, 256)        : cls positive  (a0 = (g/128)*2, p = g%128), label 1
//   [256, 514)      : cls negative  (j = g-256; a0 = (j/129)*2, n = j%129), label 0
//   [514, 578)      : regression    (k = g-514; a = k&1, m = k>>1), 7 components
//
// vs previous version (single 640-thread block on ONE CU): the gathers are
// scattered cold-HBM misses (the harness's 444 MB poison fill evicts L2/L3
// right before we run), so the kernel was bounded by a single CU's
// memory-level parallelism. Spreading the SAME item mapping across 10 blocks
// of 64 puts the gathers on 10 CUs concurrently.
//
// Reduction: 64-lane shuffle per wave -> partial[w] in d_ws, then a trailing
// 1-thread kernel sums partial[0..9] sequentially. This is bit-identical to
// the previous (wave shuffle -> wsum[w] -> sequential sum) reduction order.

#define BLOCK 64
#define NBLOCKS 10  // 10*64 = 640 threads, same layout as before

__global__ __launch_bounds__(BLOCK) void loss_partial_kernel(
    const float* __restrict__ rb,      // (B, M, 7)
    const float* __restrict__ pc,      // (B, 4, H, W)
    const float* __restrict__ pr,      // (B, 14, H, W)
    const float* __restrict__ anchor,  // (2, 7, H, W)
    const int* __restrict__ pidx,      // (B, P, 2)
    const int* __restrict__ nidx,      // (B, NN, 2)
    const int* __restrict__ ridx,      // (B, M, R, 2)
    float* __restrict__ partial)       // (NBLOCKS,)
{
    const int g = blockIdx.x * BLOCK + threadIdx.x;
    const int b = BB - 1;

    const float* rb_b   = rb + (size_t)b * MM * 7;
    const float* pc_b   = pc + (size_t)b * 4 * HW;
    const float* pr_b   = pr + (size_t)b * 14 * HW;
    const int2*  pidx_b = (const int2*)(pidx + (size_t)b * PP * 2);
    const int2*  nidx_b = (const int2*)(nidx + (size_t)b * NNEG * 2);
    const int2*  ridx_b = (const int2*)(ridx + (size_t)b * MM * RR * 2);

    float acc = 0.0f;

    if (g < 514) {
        // ---- classification item ----
        int a0, scol;
        float inv_n;
        int2 yx;
        if (g < 256) {                // positive, label = 1
            a0   = (g >> 7) * 2;      // g/128 in {0,1} -> channel pair
            yx   = pidx_b[g & 127];
            scol = 1;
            inv_n = 1.0f / PP;
        } else {                      // negative, label = 0
            int j = g - 256;
            a0   = (j / NNEG) * 2;
            yx   = nidx_b[j % NNEG];
            scol = 0;
            inv_n = 1.0f / NNEG;
        }
        size_t pix = (size_t)yx.x * WW + yx.y;
        float l0 = pc_b[(size_t)a0       * HW + pix];
        float l1 = pc_b[(size_t)(a0 + 1) * HW + pix];
        float mx  = fmaxf(l0, l1);
        float lse = mx + logf(expf(l0 - mx) + expf(l1 - mx));
        float lbl = scol ? l1 : l0;
        acc = (lse - lbl) * inv_n;
    } else if (g < 578) {
        // ---- regression item ----
        int k = g - 514;
        int a = k & 1;
        int m = k >> 1;
        int2 yx = ridx_b[m];          // R == 1
        size_t pix = (size_t)yx.x * WW + yx.y;

        float ab[7], pb[7], rf[7];
        #pragma unroll
        for (int c = 0; c < 7; ++c) {
            ab[c] = anchor[(size_t)(a * 7 + c) * HW + pix];
            pb[c] = pr_b  [(size_t)(a * 7 + c) * HW + pix];
            rf[c] = rb_b[m * 7 + c];
        }

        float diag = sqrtf(ab[3] * ab[3] + ab[4] * ab[4]);
        float off[7];
        off[0] = (rf[0] - ab[0]) / diag;
        off[1] = (rf[1] - ab[1]) / diag;
        off[2] = (rf[2] - ab[2]) / ab[5];
        off[3] = logf(rf[3] / ab[3]);
        off[4] = logf(rf[4] / ab[4]);
        off[5] = logf(rf[5] / ab[5]);
        float dth = rf[6] - ab[6];
        off[6] = atan2f(sinf(dth), cosf(dth));

        float s = 0.0f;
        #pragma unroll
        for (int c = 0; c < 7; ++c) {
            float d = pb[c] - off[c];
            float ad = fabsf(d);
            s += (ad < 1.0f) ? 0.5f * d * d : (ad - 0.5f);
        }
        acc = s * (GAIN / (float)(RR * 2 * 7));
    }

    // ---- wave (block==wave) shuffle reduction, identical tree to before ----
    #pragma unroll
    for (int off = 32; off > 0; off >>= 1)
        acc += __shfl_down(acc, off, 64);

    if (threadIdx.x == 0) partial[blockIdx.x] = acc;
}

__global__ __launch_bounds__(64) void loss_final_kernel(
    const float* __restrict__ partial,  // (NBLOCKS,)
    float* __restrict__ out)            // scalar
{
    if (threadIdx.x == 0) {
        float t = 0.0f;
        #pragma unroll
        for (int w = 0; w < NBLOCKS; ++w) t += partial[w];
        out[0] = t;
    }
}

extern "C" void kernel_launch(void* const* d_in, const int* in_sizes, int n_in,
                              void* d_out, int out_size, void* d_ws, size_t ws_size,
                              hipStream_t stream) {
    const float* rb     = (const float*)d_in[0];
    const float* pc     = (const float*)d_in[1];
    const float* pr     = (const float*)d_in[2];
    const float* anchor = (const float*)d_in[3];
    const int*   pidx   = (const int*)d_in[4];
    const int*   nidx   = (const int*)d_in[5];
    const int*   ridx   = (const int*)d_in[6];
    float* out = (float*)d_out;
    float* partial = (float*)d_ws;  // NBLOCKS floats

    loss_partial_kernel<<<NBLOCKS, BLOCK, 0, stream>>>(
        rb, pc, pr, anchor, pidx, nidx, ridx, partial);
    loss_final_kernel<<<1, 64, 0, stream>>>(partial, out);
}